// Round 2
// baseline (4004.775 us; speedup 1.0000x reference)
//
#include <hip/hip_runtime.h>
#include <math.h>

// ---------------------------------------------------------------------------
// Problem constants
// ---------------------------------------------------------------------------
constexpr int B_  = 64;
constexpr int N_  = 197;
constexpr int C_  = 768;
constexpr int H_  = 12;
constexpr int HD_ = 64;
constexpr int NP_ = 40;    // NUM_PROP (eliminated)
constexpr int NK_ = 156;   // kept (196 - 40)
constexpr int N1_ = 196;   // N - 1
constexpr int N2_ = 157;   // 1 + kept
constexpr int MLP_ = 3072;
constexpr int M1_ = B_ * N_;   // 12608 rows (attention stage)
constexpr int M2_ = B_ * N2_;  // 10048 rows (mlp stage)
constexpr float SCALE_ = 0.125f;   // hd^-0.5
constexpr float ALPHA_ = 0.1f;
constexpr float EPS_   = 1e-5f;
// int(197*197*0.75) = 29106 (descending idx) -> ascending k = 38809-1-29106
constexpr int KASC_ATTN = N_ * N_ - 1 - 29106;   // 9702
// int(156*40*0.05) = 312 (descending idx)    -> ascending k = 6240-1-312
constexpr int KASC_W    = NK_ * NP_ - 1 - 312;   // 5927

// ---------------------------------------------------------------------------
// Workspace layout (floats). Liveness-overlaid; peak = stage 3 (q,k,v,attn).
//   [0, 29.8M)        : h (st1-2) -> attn (st3-8) -> h2[0,7.7M) + fc1h[7.7M,38.6M)
//   [29.8M, 39.5M)    : q (st2-3) -> x1 (st7-10)
//   [39.5M, 49.2M)    : k (st2-3) -> aout (st5-7)
//   [49.2M, 58.9M)    : v (st2-5) -> wbuf (st8-10)
//   [58.85M, +26624)  : sig, wsig, tr, ord
// x2 lives in d_out (exactly out_size elements).
// Total: 58,880,768 floats = 235,523,072 bytes (~224.6 MiB)
// ---------------------------------------------------------------------------
constexpr size_t OFF_ATTN = 0;
constexpr size_t OFF_H    = 0;
constexpr size_t OFF_H2   = 0;
constexpr size_t OFF_FC1H = (size_t)M2_ * C_;                 //  7,716,864
constexpr size_t OFF_Q    = (size_t)B_ * H_ * N_ * N_;        // 29,805,312
constexpr size_t OFF_K    = OFF_Q + (size_t)M1_ * C_;         // 39,488,256
constexpr size_t OFF_V    = OFF_K + (size_t)M1_ * C_;         // 49,171,200
constexpr size_t OFF_X1   = OFF_Q;
constexpr size_t OFF_AOUT = OFF_K;
constexpr size_t OFF_WBUF = OFF_V;
constexpr size_t OFF_SIG  = OFF_V + (size_t)M1_ * C_;         // 58,854,144
constexpr size_t OFF_WSIG = OFF_SIG + B_ * H_;
constexpr size_t OFF_TR   = OFF_WSIG + B_ * H_;
constexpr size_t OFF_ORD  = OFF_TR + B_ * N1_;

// ---------------------------------------------------------------------------
// Helpers
// ---------------------------------------------------------------------------
__device__ __forceinline__ float block_reduce_sum(float v, float* red) {
  #pragma unroll
  for (int off = 32; off; off >>= 1) v += __shfl_xor(v, off);
  if ((threadIdx.x & 63) == 0) red[threadIdx.x >> 6] = v;
  __syncthreads();
  float r = red[0] + red[1] + red[2] + red[3];
  __syncthreads();
  return r;
}

// ---------------------------------------------------------------------------
// LayerNorm: one block (256 thr) per row of 768
// ---------------------------------------------------------------------------
__global__ __launch_bounds__(256) void ln_kernel(
    const float* __restrict__ x, const float* __restrict__ w,
    const float* __restrict__ b, float* __restrict__ out)
{
  __shared__ float red[4];
  const size_t row = blockIdx.x;
  const float* xr = x + row * C_;
  float* orow = out + row * C_;
  const int t = threadIdx.x;
  float v[3];
  float s = 0.f;
  #pragma unroll
  for (int i = 0; i < 3; ++i) { v[i] = xr[t + 256 * i]; s += v[i]; }
  const float mu = block_reduce_sum(s, red) * (1.f / 768.f);
  s = 0.f;
  #pragma unroll
  for (int i = 0; i < 3; ++i) { float d = v[i] - mu; s += d * d; }
  const float var = block_reduce_sum(s, red) * (1.f / 768.f);
  const float rs = rsqrtf(var + EPS_);
  #pragma unroll
  for (int i = 0; i < 3; ++i) {
    int c = t + 256 * i;
    orow[c] = (v[i] - mu) * rs * w[c] + b[c];
  }
}

// ---------------------------------------------------------------------------
// Generic SGEMM:  C[m,n] = sum_k A[m,k] * Bw[n,k]  (+bias, +gelu, +residual)
// M % 64 == 0, Nn % 64 == 0, K % 16 == 0 (all shapes here satisfy this)
// ---------------------------------------------------------------------------
__global__ __launch_bounds__(256) void gemm_kernel(
    const float* __restrict__ A, const float* __restrict__ Bw,
    const float* __restrict__ bias, const float* __restrict__ res,
    float* __restrict__ Cm, int M, int Nn, int K, int act)
{
  __shared__ __align__(16) float As[16][72];
  __shared__ __align__(16) float Bs[16][72];
  const int t  = threadIdx.x;
  const int tx = t & 15;    // n-group
  const int ty = t >> 4;    // m-group
  const int m0 = blockIdx.y * 64;
  const int n0 = blockIdx.x * 64;
  const int lm = t >> 2;          // 0..63
  const int lk = (t & 3) << 2;    // 0,4,8,12
  float acc[4][4] = {};
  const float* Ap = A  + (size_t)(m0 + lm) * K + lk;
  const float* Bp = Bw + (size_t)(n0 + lm) * K + lk;
  for (int k0 = 0; k0 < K; k0 += 16) {
    const float4 a4 = *(const float4*)(Ap + k0);
    const float4 b4 = *(const float4*)(Bp + k0);
    As[lk + 0][lm] = a4.x; As[lk + 1][lm] = a4.y;
    As[lk + 2][lm] = a4.z; As[lk + 3][lm] = a4.w;
    Bs[lk + 0][lm] = b4.x; Bs[lk + 1][lm] = b4.y;
    Bs[lk + 2][lm] = b4.z; Bs[lk + 3][lm] = b4.w;
    __syncthreads();
    #pragma unroll
    for (int kk = 0; kk < 16; ++kk) {
      const float4 av = *(const float4*)&As[kk][ty * 4];
      const float4 bv = *(const float4*)&Bs[kk][tx * 4];
      const float am[4] = {av.x, av.y, av.z, av.w};
      const float bn[4] = {bv.x, bv.y, bv.z, bv.w};
      #pragma unroll
      for (int i = 0; i < 4; ++i)
        #pragma unroll
        for (int j = 0; j < 4; ++j)
          acc[i][j] += am[i] * bn[j];
    }
    __syncthreads();
  }
  #pragma unroll
  for (int i = 0; i < 4; ++i) {
    const int m = m0 + ty * 4 + i;
    #pragma unroll
    for (int j = 0; j < 4; ++j) {
      const int n = n0 + tx * 4 + j;
      float v = acc[i][j];
      if (bias) v += bias[n];
      if (act == 1) v = 0.5f * v * (1.0f + erff(v * 0.7071067811865476f));
      if (res) v += res[(size_t)m * Nn + n];
      Cm[(size_t)m * Nn + n] = v;
    }
  }
}

// ---------------------------------------------------------------------------
// Attention scores from separate q,k buffers (each M1 x 768, head-major cols).
// One block per (b,h); S[n,j] = scale * q_n . k_j
// ---------------------------------------------------------------------------
__global__ __launch_bounds__(256) void attn_scores_kernel(
    const float* __restrict__ q, const float* __restrict__ k,
    float* __restrict__ attn)
{
  const int bh = blockIdx.x;
  const int b = bh / H_, h = bh % H_;
  __shared__ __align__(16) float Ks[N_][72];
  __shared__ __align__(16) float qs[HD_];
  for (int idx = threadIdx.x; idx < N_ * HD_; idx += 256) {
    const int j = idx / HD_, d = idx % HD_;
    Ks[j][d] = k[((size_t)(b * N_ + j)) * C_ + h * HD_ + d];
  }
  __syncthreads();
  float* arow = attn + (size_t)bh * N_ * N_;
  for (int n = 0; n < N_; ++n) {
    if (threadIdx.x < HD_)
      qs[threadIdx.x] =
          q[((size_t)(b * N_ + n)) * C_ + h * HD_ + threadIdx.x] * SCALE_;
    __syncthreads();
    for (int j = threadIdx.x; j < N_; j += 256) {
      const float4* kr = (const float4*)&Ks[j][0];
      const float4* qr = (const float4*)qs;
      float acc = 0.f;
      #pragma unroll
      for (int d4 = 0; d4 < 16; ++d4) {
        const float4 kv = kr[d4];
        const float4 qv = qr[d4];
        acc += qv.x * kv.x + qv.y * kv.y + qv.z * kv.z + qv.w * kv.w;
      }
      arow[(size_t)n * N_ + j] = acc;
    }
    __syncthreads();
  }
}

// ---------------------------------------------------------------------------
// Softmax along last dim (197). One wave per row, 4 rows per block.
// ---------------------------------------------------------------------------
__global__ __launch_bounds__(256) void softmax_kernel(float* __restrict__ attn)
{
  const int row = blockIdx.x * 4 + (threadIdx.x >> 6);
  const int lane = threadIdx.x & 63;
  float* r = attn + (size_t)row * N_;
  float vals[4];
  float m = -1e30f;
  int cnt = 0;
  for (int j = lane; j < N_; j += 64) { vals[cnt] = r[j]; m = fmaxf(m, vals[cnt]); ++cnt; }
  #pragma unroll
  for (int off = 32; off; off >>= 1) m = fmaxf(m, __shfl_xor(m, off));
  float s = 0.f;
  for (int i = 0; i < cnt; ++i) { vals[i] = expf(vals[i] - m); s += vals[i]; }
  #pragma unroll
  for (int off = 32; off; off >>= 1) s += __shfl_xor(s, off);
  const float inv = 1.0f / s;
  cnt = 0;
  for (int j = lane; j < N_; j += 64) { r[j] = vals[cnt] * inv; ++cnt; }
}

// ---------------------------------------------------------------------------
// Radix select: per-segment k-th smallest (ascending, 0-indexed) of `count`
// non-negative floats. One block (256 thr) per segment. Exact.
// ---------------------------------------------------------------------------
__global__ __launch_bounds__(256) void radix_select_kernel(
    const float* __restrict__ data, int count, int k, int stride,
    float* __restrict__ out)
{
  const float* seg = data + (size_t)blockIdx.x * stride;
  __shared__ unsigned int hist[256];
  __shared__ unsigned int prefix_s;
  __shared__ int k_s;
  unsigned int prefix = 0u;
  int kk = k;
  for (int pass = 3; pass >= 0; --pass) {
    const int shift = pass * 8;
    hist[threadIdx.x] = 0u;
    __syncthreads();
    const unsigned int mask_known =
        (pass == 3) ? 0u : (0xFFFFFFFFu << ((pass + 1) * 8));
    for (int i = threadIdx.x; i < count; i += 256) {
      const unsigned int bits = __float_as_uint(seg[i]);
      if ((bits & mask_known) == prefix)
        atomicAdd(&hist[(bits >> shift) & 0xFFu], 1u);
    }
    __syncthreads();
    if (threadIdx.x == 0) {
      int rem = kk;
      unsigned int d = 0;
      for (; d < 256u; ++d) {
        if (rem < (int)hist[d]) break;
        rem -= (int)hist[d];
      }
      prefix_s = prefix | (d << shift);
      k_s = rem;
    }
    __syncthreads();
    prefix = prefix_s;
    kk = k_s;
    __syncthreads();
  }
  if (threadIdx.x == 0) out[blockIdx.x] = __uint_as_float(prefix);
}

// ---------------------------------------------------------------------------
// Threshold: a[i] = a[i] >= sig[i/seglen] ? a[i] : 0
// ---------------------------------------------------------------------------
__global__ __launch_bounds__(256) void threshold_kernel(
    float* __restrict__ a, const float* __restrict__ sig, int total, int seglen)
{
  const int idx = blockIdx.x * 256 + threadIdx.x;
  if (idx >= total) return;
  const float v = a[idx];
  if (v < sig[idx / seglen]) a[idx] = 0.0f;
}

// ---------------------------------------------------------------------------
// attn @ v : one block per (b,h); v is M1 x 768 head-major; out (B,N,C)
// ---------------------------------------------------------------------------
__global__ __launch_bounds__(256) void attn_v_kernel(
    const float* __restrict__ attn, const float* __restrict__ v,
    float* __restrict__ out)
{
  const int bh = blockIdx.x;
  const int b = bh / H_, h = bh % H_;
  __shared__ float Vs[N_ * HD_];
  for (int idx = threadIdx.x; idx < N_ * HD_; idx += 256) {
    const int j = idx / HD_, d = idx % HD_;
    Vs[idx] = v[((size_t)(b * N_ + j)) * C_ + h * HD_ + d];
  }
  __syncthreads();
  const int rg = threadIdx.x >> 6, d = threadIdx.x & 63;
  const float* abase = attn + (size_t)bh * N_ * N_;
  for (int n = rg; n < N_; n += 4) {
    const float* ar = abase + (size_t)n * N_;
    float acc = 0.f;
    for (int j = 0; j < N_; ++j) acc += ar[j] * Vs[j * HD_ + d];
    out[((size_t)b * N_ + n) * C_ + h * HD_ + d] = acc;
  }
}

// ---------------------------------------------------------------------------
// token_rank[b,j] = mean_h attn[b,h,j+1,j+1]   (after thresholding)
// ---------------------------------------------------------------------------
__global__ __launch_bounds__(256) void token_rank_kernel(
    const float* __restrict__ attn, float* __restrict__ tr)
{
  const int b = blockIdx.x;
  for (int j = threadIdx.x; j < N1_; j += 256) {
    const int n = j + 1;
    float s = 0.f;
    #pragma unroll
    for (int h = 0; h < H_; ++h)
      s += attn[(((size_t)(b * H_ + h)) * N_ + n) * N_ + n];
    tr[b * N1_ + j] = s * (1.f / H_);
  }
}

// ---------------------------------------------------------------------------
// Stable descending argsort of 196 values per batch via rank counting.
// ---------------------------------------------------------------------------
__global__ __launch_bounds__(256) void order_kernel(
    const float* __restrict__ tr, int* __restrict__ order)
{
  const int b = blockIdx.x;
  __shared__ float v[N1_];
  const int t = threadIdx.x;
  if (t < N1_) v[t] = tr[b * N1_ + t];
  __syncthreads();
  if (t < N1_) {
    const float mv = v[t];
    int r = 0;
    for (int i = 0; i < N1_; ++i) {
      const float vi = v[i];
      r += (vi > mv) || (vi == mv && i < t);
    }
    order[b * N1_ + r] = t;
  }
}

// ---------------------------------------------------------------------------
// w[b,h,i,j] = attn[b,h, kept_i, elim_j]
// ---------------------------------------------------------------------------
__global__ __launch_bounds__(256) void w_gather_kernel(
    const float* __restrict__ attn, const int* __restrict__ ord,
    float* __restrict__ w)
{
  const int idx = blockIdx.x * 256 + threadIdx.x;
  if (idx >= B_ * H_ * NK_ * NP_) return;
  const int e = idx % NP_;
  const int k = (idx / NP_) % NK_;
  const int h = (idx / (NP_ * NK_)) % H_;
  const int b = idx / (NP_ * NK_ * H_);
  const int ki = ord[b * N1_ + k] + 1;
  const int ej = ord[b * N1_ + NK_ + e] + 1;
  w[idx] = attn[(((size_t)b * H_ + h) * N_ + ki) * N_ + ej];
}

// ---------------------------------------------------------------------------
// x_prop + assemble x2 = concat(cls, kept + alpha*prop). grid (157, B)
// ---------------------------------------------------------------------------
__global__ __launch_bounds__(256) void xprop_kernel(
    const float* __restrict__ x1, const float* __restrict__ w,
    const int* __restrict__ ord, float* __restrict__ x2)
{
  const int b = blockIdx.y;
  const int kk = blockIdx.x;   // 0..156
  const int t = threadIdx.x;
  if (kk == 0) {
    for (int c = t; c < C_; c += 256)
      x2[(size_t)b * N2_ * C_ + c] = x1[(size_t)b * N_ * C_ + c];
    return;
  }
  const int k = kk - 1;
  __shared__ float ws_[H_ * NP_];
  __shared__ int es[NP_];
  if (t < NP_) es[t] = ord[b * N1_ + NK_ + t] + 1;
  for (int i = t; i < H_ * NP_; i += 256) {
    const int h = i / NP_, e = i % NP_;
    ws_[i] = w[(((size_t)b * H_ + h) * NK_ + k) * NP_ + e];
  }
  __syncthreads();
  const int kept = ord[b * N1_ + k] + 1;
  const float* xk = x1 + ((size_t)b * N_ + kept) * C_;
  float* xo = x2 + ((size_t)b * N2_ + 1 + k) * C_;
  for (int c = t; c < C_; c += 256) {
    const int h = c >> 6;
    float acc = 0.f;
    #pragma unroll 8
    for (int e = 0; e < NP_; ++e)
      acc += ws_[h * NP_ + e] * x1[((size_t)b * N_ + es[e]) * C_ + c];
    xo[c] = xk[c] + ALPHA_ * acc;
  }
}

// ---------------------------------------------------------------------------
// Launcher
// ---------------------------------------------------------------------------
extern "C" void kernel_launch(void* const* d_in, const int* in_sizes, int n_in,
                              void* d_out, int out_size, void* d_ws, size_t ws_size,
                              hipStream_t stream)
{
  const float* x     = (const float*)d_in[0];
  const float* n1w   = (const float*)d_in[1];
  const float* n1b   = (const float*)d_in[2];
  const float* qkvw  = (const float*)d_in[3];
  const float* projw = (const float*)d_in[4];
  const float* projb = (const float*)d_in[5];
  const float* n2w   = (const float*)d_in[6];
  const float* n2b   = (const float*)d_in[7];
  const float* fc1w  = (const float*)d_in[8];
  const float* fc1b  = (const float*)d_in[9];
  const float* fc2w  = (const float*)d_in[10];
  const float* fc2b  = (const float*)d_in[11];
  float* outp = (float*)d_out;

  float* ws   = (float*)d_ws;
  float* h    = ws + OFF_H;
  float* attn = ws + OFF_ATTN;
  float* qb   = ws + OFF_Q;
  float* kb   = ws + OFF_K;
  float* vb   = ws + OFF_V;
  float* x1   = ws + OFF_X1;
  float* aout = ws + OFF_AOUT;
  float* wbuf = ws + OFF_WBUF;
  float* h2   = ws + OFF_H2;
  float* fc1h = ws + OFF_FC1H;
  float* sig  = ws + OFF_SIG;
  float* wsig = ws + OFF_WSIG;
  float* tr   = ws + OFF_TR;
  int*   ord  = (int*)(ws + OFF_ORD);
  float* x2   = outp;   // x2 lives in d_out (exactly out_size elements)

  // 1. LN1
  ln_kernel<<<M1_, 256, 0, stream>>>(x, n1w, n1b, h);
  // 2. q/k/v = h @ qkv_w[part].T  (three M1 x 768 GEMMs)
  gemm_kernel<<<dim3(C_ / 64, M1_ / 64), 256, 0, stream>>>(
      h, qkvw,               nullptr, nullptr, qb, M1_, C_, C_, 0);
  gemm_kernel<<<dim3(C_ / 64, M1_ / 64), 256, 0, stream>>>(
      h, qkvw + (size_t)C_ * C_,     nullptr, nullptr, kb, M1_, C_, C_, 0);
  gemm_kernel<<<dim3(C_ / 64, M1_ / 64), 256, 0, stream>>>(
      h, qkvw + (size_t)2 * C_ * C_, nullptr, nullptr, vb, M1_, C_, C_, 0);
  // 3. scores (overwrites h region; h is dead)
  attn_scores_kernel<<<B_ * H_, 256, 0, stream>>>(qb, kb, attn);
  // 4. softmax
  softmax_kernel<<<(B_ * H_ * N_) / 4, 256, 0, stream>>>(attn);
  // 5. sigma per (b,h) + threshold
  radix_select_kernel<<<B_ * H_, 256, 0, stream>>>(attn, N_ * N_, KASC_ATTN,
                                                   N_ * N_, sig);
  {
    const int total = B_ * H_ * N_ * N_;
    threshold_kernel<<<(total + 255) / 256, 256, 0, stream>>>(attn, sig, total,
                                                              N_ * N_);
  }
  // 6. out = attn @ v  (into aout, k-slot; k is dead)
  attn_v_kernel<<<B_ * H_, 256, 0, stream>>>(attn, vb, aout);
  // 7. token_rank + stable order
  token_rank_kernel<<<B_, 256, 0, stream>>>(attn, tr);
  order_kernel<<<B_, 256, 0, stream>>>(tr, ord);
  // 8. x1 = x + aout @ proj_w.T + proj_b  (into q-slot; q is dead)
  gemm_kernel<<<dim3(C_ / 64, M1_ / 64), 256, 0, stream>>>(
      aout, projw, projb, x, x1, M1_, C_, C_, 0);
  // 9. w gather (into v-slot; v is dead) + w_sigma + threshold
  {
    const int total = B_ * H_ * NK_ * NP_;
    w_gather_kernel<<<(total + 255) / 256, 256, 0, stream>>>(attn, ord, wbuf);
    radix_select_kernel<<<B_ * H_, 256, 0, stream>>>(wbuf, NK_ * NP_, KASC_W,
                                                     NK_ * NP_, wsig);
    threshold_kernel<<<(total + 255) / 256, 256, 0, stream>>>(wbuf, wsig, total,
                                                              NK_ * NP_);
  }
  // 10. x_prop + assemble x2 (into d_out; attn dead hereafter)
  xprop_kernel<<<dim3(N2_, B_), 256, 0, stream>>>(x1, wbuf, ord, x2);
  // 11. LN2 (h2 into start of old attn region)
  ln_kernel<<<M2_, 256, 0, stream>>>(x2, n2w, n2b, h2);
  // 12. fc1 + bias + exact gelu (fc1h after h2 in old attn region)
  gemm_kernel<<<dim3(MLP_ / 64, M2_ / 64), 256, 0, stream>>>(
      h2, fc1w, fc1b, nullptr, fc1h, M2_, MLP_, C_, 1);
  // 13. out = x2 + fc1h @ fc2_w.T + fc2_b  (in-place residual on d_out: each
  //     element is read-then-written by the same thread exactly once)
  gemm_kernel<<<dim3(C_ / 64, M2_ / 64), 256, 0, stream>>>(
      fc1h, fc2w, fc2b, x2, outp, M2_, C_, MLP_, 0);
}

// Round 3
// 2024.752 us; speedup vs baseline: 1.9779x; 1.9779x over previous
//
#include <hip/hip_runtime.h>
#include <math.h>

// ---------------------------------------------------------------------------
// Problem constants
// ---------------------------------------------------------------------------
constexpr int B_  = 64;
constexpr int N_  = 197;
constexpr int C_  = 768;
constexpr int H_  = 12;
constexpr int HD_ = 64;
constexpr int NP_ = 40;
constexpr int NK_ = 156;
constexpr int N1_ = 196;
constexpr int N2_ = 157;
constexpr int MLP_ = 3072;
constexpr int M1_ = B_ * N_;    // 12608
constexpr int M2_ = B_ * N2_;   // 10048
constexpr int M1P_ = 12672;     // pad to 128
constexpr int M2P_ = 10112;     // pad to 128
constexpr float SCALE_ = 0.125f;
constexpr float ALPHA_ = 0.1f;
constexpr float EPS_   = 1e-5f;
constexpr int KASC_ATTN = N_ * N_ - 1 - 29106;   // 9702
constexpr int KASC_W    = NK_ * NP_ - 1 - 312;   // 5927

typedef __bf16 bf16x8 __attribute__((ext_vector_type(8)));
typedef float  floatx4 __attribute__((ext_vector_type(4)));

// ---------------------------------------------------------------------------
// Workspace layout (byte offsets). Liveness-overlaid. Total ~224.9 MB
// (round-2's 235.5 MB layout worked, so this is under the proven bound).
// Region A [0, 119,221,248): xa_hi/xa_lo -> attn -> fc1h + h2 + fc1w/fc2w(bf16)
// Region B [119,221,248, 216,542,208): qk(fp32)+vb(bf16) -> x1 + aout + wbuf
// Region W [216,542,208, 224,799,744): qkvw_hi/lo, projw (bf16)
// smalls   [224,799,744, ...): sig, wsig, tr, ord
// ---------------------------------------------------------------------------
constexpr size_t A_B     = 0;
constexpr size_t OFFB_XAHI = A_B;                        // bf16 M1P*C
constexpr size_t OFFB_XALO = A_B + 19464192;             // bf16 M1P*C
constexpr size_t OFFB_ATTN = A_B;                        // fp32 768*197*197
constexpr size_t OFFB_FC1H = A_B;                        // bf16 M2P*3072
constexpr size_t OFFB_H2   = A_B + 62128128;             // bf16 M2P*768
constexpr size_t OFFB_FC1W = A_B + 77660160;             // bf16 3072*768
constexpr size_t OFFB_FC2W = A_B + 82378752;             // bf16 768*3072
constexpr size_t B_B     = 119221248;
constexpr size_t OFFB_QK   = B_B;                        // fp32 M1P*1536
constexpr size_t OFFB_VB   = B_B + 77856768;             // bf16 M1P*768
constexpr size_t OFFB_X1   = B_B;                        // fp32 M1P*768
constexpr size_t OFFB_AOUT = B_B + 38928384;             // bf16 M1P*768
constexpr size_t OFFB_WBUF = B_B + 77856768;             // fp32 768*156*40
constexpr size_t W_B     = 216542208;
constexpr size_t OFFB_QWHI = W_B;                        // bf16 2304*768
constexpr size_t OFFB_QWLO = W_B + 3538944;
constexpr size_t OFFB_PRJW = W_B + 7077888;              // bf16 768*768
constexpr size_t S_B     = 224799744;
constexpr size_t OFFB_SIG  = S_B;
constexpr size_t OFFB_WSIG = S_B + 3072;
constexpr size_t OFFB_TR   = S_B + 6144;
constexpr size_t OFFB_ORD  = S_B + 56320;

// ---------------------------------------------------------------------------
// Weight conversion kernels
// ---------------------------------------------------------------------------
__global__ __launch_bounds__(256) void wsplit_kernel(
    const float* __restrict__ w, __bf16* __restrict__ hi,
    __bf16* __restrict__ lo, int n)
{
  const int i = blockIdx.x * 256 + threadIdx.x;
  if (i >= n) return;
  const float v = w[i];
  const __bf16 h = (__bf16)v;
  hi[i] = h;
  lo[i] = (__bf16)(v - (float)h);
}

__global__ __launch_bounds__(256) void wconv_kernel(
    const float* __restrict__ w, __bf16* __restrict__ o, int n)
{
  const int i = blockIdx.x * 256 + threadIdx.x;
  if (i < n) o[i] = (__bf16)w[i];
}

// ---------------------------------------------------------------------------
// Helpers
// ---------------------------------------------------------------------------
__device__ __forceinline__ float block_reduce_sum(float v, float* red) {
  #pragma unroll
  for (int off = 32; off; off >>= 1) v += __shfl_xor(v, off);
  if ((threadIdx.x & 63) == 0) red[threadIdx.x >> 6] = v;
  __syncthreads();
  float r = red[0] + red[1] + red[2] + red[3];
  __syncthreads();
  return r;
}

// ---------------------------------------------------------------------------
// LayerNorm -> bf16 (optionally split hi/lo). Pad rows (>= Mvalid) -> zeros.
// ---------------------------------------------------------------------------
__global__ __launch_bounds__(256) void ln_bf16_kernel(
    const float* __restrict__ x, const float* __restrict__ w,
    const float* __restrict__ b, __bf16* __restrict__ ohi,
    __bf16* __restrict__ olo, int Mvalid)
{
  __shared__ float red[4];
  const size_t row = blockIdx.x;
  const int t = threadIdx.x;
  if ((int)row >= Mvalid) {
    #pragma unroll
    for (int i = 0; i < 3; ++i) {
      ohi[row * C_ + t + 256 * i] = (__bf16)0.f;
      if (olo) olo[row * C_ + t + 256 * i] = (__bf16)0.f;
    }
    return;
  }
  const float* xr = x + row * C_;
  float v[3];
  float s = 0.f;
  #pragma unroll
  for (int i = 0; i < 3; ++i) { v[i] = xr[t + 256 * i]; s += v[i]; }
  const float mu = block_reduce_sum(s, red) * (1.f / 768.f);
  s = 0.f;
  #pragma unroll
  for (int i = 0; i < 3; ++i) { float d = v[i] - mu; s += d * d; }
  const float var = block_reduce_sum(s, red) * (1.f / 768.f);
  const float rs = rsqrtf(var + EPS_);
  #pragma unroll
  for (int i = 0; i < 3; ++i) {
    const int c = t + 256 * i;
    const float val = (v[i] - mu) * rs * w[c] + b[c];
    const __bf16 h = (__bf16)val;
    ohi[row * C_ + c] = h;
    if (olo) olo[row * C_ + c] = (__bf16)(val - (float)h);
  }
}

// ---------------------------------------------------------------------------
// MFMA tile staging: 128x32 bf16 tile, global -> LDS via global_load_lds x16B
// LDS layout row-major [128][32]; dst constraint: wave-uniform base + lane*16.
// ---------------------------------------------------------------------------
__device__ __forceinline__ void stage_tile(
    const __bf16* __restrict__ gbase, int ldg, __bf16* lds, int wave, int lane)
{
  #pragma unroll
  for (int j = 0; j < 2; ++j) {
    const int seg = 4 * j + wave;                 // 0..7, 16 rows each
    const int row = seg * 16 + (lane >> 2);
    const int col = (lane & 3) * 8;
    const __bf16* g = gbase + (size_t)row * ldg + col;
    __bf16* l = lds + seg * 512 + lane * 8;       // == base + lane*16B
    __builtin_amdgcn_global_load_lds(
        (const __attribute__((address_space(1))) unsigned int*)g,
        (__attribute__((address_space(3))) unsigned int*)l, 16, 0, 0);
  }
}

__device__ __forceinline__ bf16x8 frag(const __bf16* lds, int r, int hi8) {
  return *(const bf16x8*)(lds + r * 32 + hi8);
}

// ---------------------------------------------------------------------------
// Plain bf16 MFMA GEMM: C[m,n] = sum_k A[m,k]*Bw[n,k] (+bias,+gelu,+res)
// A [>=ceil128(M) x K] bf16, Bw [Nn x K] bf16. Stores rows < Mstore.
// ---------------------------------------------------------------------------
__global__ __launch_bounds__(256) void gemm_bf16_kernel(
    const __bf16* __restrict__ A, const __bf16* __restrict__ Bw,
    const float* __restrict__ bias, const float* __restrict__ res,
    float* __restrict__ outf, __bf16* __restrict__ outb,
    int Mstore, int Nn, int K, int act)
{
  __shared__ __bf16 As[128 * 32];
  __shared__ __bf16 Bs[128 * 32];
  const int t = threadIdx.x;
  const int wave = t >> 6, lane = t & 63;
  const int m0 = blockIdx.y * 128, n0 = blockIdx.x * 128;
  const int wm = (wave >> 1) * 64, wn = (wave & 1) * 64;
  const int lo = lane & 15, hi8 = (lane >> 4) * 8;
  floatx4 acc[4][4] = {};
  for (int k0 = 0; k0 < K; k0 += 32) {
    stage_tile(A + (size_t)m0 * K + k0, K, As, wave, lane);
    stage_tile(Bw + (size_t)n0 * K + k0, K, Bs, wave, lane);
    __syncthreads();
    bf16x8 af[4], bfr[4];
    #pragma unroll
    for (int i = 0; i < 4; ++i) af[i]  = frag(As, wm + i * 16 + lo, hi8);
    #pragma unroll
    for (int j = 0; j < 4; ++j) bfr[j] = frag(Bs, wn + j * 16 + lo, hi8);
    #pragma unroll
    for (int i = 0; i < 4; ++i)
      #pragma unroll
      for (int j = 0; j < 4; ++j)
        acc[i][j] = __builtin_amdgcn_mfma_f32_16x16x32_bf16(
            af[i], bfr[j], acc[i][j], 0, 0, 0);
    __syncthreads();
  }
  #pragma unroll
  for (int i = 0; i < 4; ++i) {
    #pragma unroll
    for (int j = 0; j < 4; ++j) {
      #pragma unroll
      for (int r = 0; r < 4; ++r) {
        const int m = m0 + wm + i * 16 + (lane >> 4) * 4 + r;
        const int n = n0 + wn + j * 16 + lo;
        if (m < Mstore) {
          float v = acc[i][j][r];
          if (bias) v += bias[n];
          if (act) v = 0.5f * v * (1.0f + erff(v * 0.7071067811865476f));
          if (res) v += res[(size_t)m * Nn + n];
          if (outf) outf[(size_t)m * Nn + n] = v;
          else      outb[(size_t)m * Nn + n] = (__bf16)v;
        }
      }
    }
  }
}

// ---------------------------------------------------------------------------
// Split-bf16 MFMA GEMM (fp32-grade): acc = Ah*Bh + Ah*Bl + Al*Bh, fp32 out.
// Used for q,k so token-ordering decisions stay numerically safe.
// ---------------------------------------------------------------------------
__global__ __launch_bounds__(256) void gemm_split_kernel(
    const __bf16* __restrict__ Ah, const __bf16* __restrict__ Al,
    const __bf16* __restrict__ Bh, const __bf16* __restrict__ Bl,
    float* __restrict__ outf, int Nn, int K)
{
  __shared__ __bf16 Ahs[128 * 32];
  __shared__ __bf16 Als[128 * 32];
  __shared__ __bf16 Bhs[128 * 32];
  __shared__ __bf16 Bls[128 * 32];
  const int t = threadIdx.x;
  const int wave = t >> 6, lane = t & 63;
  const int m0 = blockIdx.y * 128, n0 = blockIdx.x * 128;
  const int wm = (wave >> 1) * 64, wn = (wave & 1) * 64;
  const int lo = lane & 15, hi8 = (lane >> 4) * 8;
  floatx4 acc[4][4] = {};
  for (int k0 = 0; k0 < K; k0 += 32) {
    stage_tile(Ah + (size_t)m0 * K + k0, K, Ahs, wave, lane);
    stage_tile(Al + (size_t)m0 * K + k0, K, Als, wave, lane);
    stage_tile(Bh + (size_t)n0 * K + k0, K, Bhs, wave, lane);
    stage_tile(Bl + (size_t)n0 * K + k0, K, Bls, wave, lane);
    __syncthreads();
    bf16x8 ah[4], al[4], bh[4], bl[4];
    #pragma unroll
    for (int i = 0; i < 4; ++i) {
      ah[i] = frag(Ahs, wm + i * 16 + lo, hi8);
      al[i] = frag(Als, wm + i * 16 + lo, hi8);
    }
    #pragma unroll
    for (int j = 0; j < 4; ++j) {
      bh[j] = frag(Bhs, wn + j * 16 + lo, hi8);
      bl[j] = frag(Bls, wn + j * 16 + lo, hi8);
    }
    #pragma unroll
    for (int i = 0; i < 4; ++i)
      #pragma unroll
      for (int j = 0; j < 4; ++j) {
        acc[i][j] = __builtin_amdgcn_mfma_f32_16x16x32_bf16(
            ah[i], bh[j], acc[i][j], 0, 0, 0);
        acc[i][j] = __builtin_amdgcn_mfma_f32_16x16x32_bf16(
            ah[i], bl[j], acc[i][j], 0, 0, 0);
        acc[i][j] = __builtin_amdgcn_mfma_f32_16x16x32_bf16(
            al[i], bh[j], acc[i][j], 0, 0, 0);
      }
    __syncthreads();
  }
  #pragma unroll
  for (int i = 0; i < 4; ++i)
    #pragma unroll
    for (int j = 0; j < 4; ++j)
      #pragma unroll
      for (int r = 0; r < 4; ++r) {
        const int m = m0 + wm + i * 16 + (lane >> 4) * 4 + r;
        const int n = n0 + wn + j * 16 + lo;
        outf[(size_t)m * Nn + n] = acc[i][j][r];
      }
}

// ---------------------------------------------------------------------------
// Attention scores: qk fp32 [M1P x 1536] (q cols 0..767, k cols 768..1535)
// ---------------------------------------------------------------------------
__global__ __launch_bounds__(256) void attn_scores_kernel(
    const float* __restrict__ qk, float* __restrict__ attn)
{
  const int bh = blockIdx.x;
  const int b = bh / H_, h = bh % H_;
  __shared__ __align__(16) float Ks[N_][72];
  __shared__ __align__(16) float qs[HD_];
  for (int idx = threadIdx.x; idx < N_ * HD_; idx += 256) {
    const int j = idx / HD_, d = idx % HD_;
    Ks[j][d] = qk[((size_t)(b * N_ + j)) * 1536 + 768 + h * HD_ + d];
  }
  __syncthreads();
  float* arow = attn + (size_t)bh * N_ * N_;
  for (int n = 0; n < N_; ++n) {
    if (threadIdx.x < HD_)
      qs[threadIdx.x] =
          qk[((size_t)(b * N_ + n)) * 1536 + h * HD_ + threadIdx.x] * SCALE_;
    __syncthreads();
    for (int j = threadIdx.x; j < N_; j += 256) {
      const float4* kr = (const float4*)&Ks[j][0];
      const float4* qr = (const float4*)qs;
      float acc = 0.f;
      #pragma unroll
      for (int d4 = 0; d4 < 16; ++d4) {
        const float4 kv = kr[d4];
        const float4 qv = qr[d4];
        acc += qv.x * kv.x + qv.y * kv.y + qv.z * kv.z + qv.w * kv.w;
      }
      arow[(size_t)n * N_ + j] = acc;
    }
    __syncthreads();
  }
}

// ---------------------------------------------------------------------------
// Softmax along last dim (197). One wave per row, 4 rows per block.
// ---------------------------------------------------------------------------
__global__ __launch_bounds__(256) void softmax_kernel(float* __restrict__ attn)
{
  const int row = blockIdx.x * 4 + (threadIdx.x >> 6);
  const int lane = threadIdx.x & 63;
  float* r = attn + (size_t)row * N_;
  float vals[4];
  float m = -1e30f;
  int cnt = 0;
  for (int j = lane; j < N_; j += 64) { vals[cnt] = r[j]; m = fmaxf(m, vals[cnt]); ++cnt; }
  #pragma unroll
  for (int off = 32; off; off >>= 1) m = fmaxf(m, __shfl_xor(m, off));
  float s = 0.f;
  for (int i = 0; i < cnt; ++i) { vals[i] = expf(vals[i] - m); s += vals[i]; }
  #pragma unroll
  for (int off = 32; off; off >>= 1) s += __shfl_xor(s, off);
  const float inv = 1.0f / s;
  cnt = 0;
  for (int j = lane; j < N_; j += 64) { r[j] = vals[cnt] * inv; ++cnt; }
}

// ---------------------------------------------------------------------------
// Radix select: per-segment k-th smallest (ascending) of non-negative floats.
// ---------------------------------------------------------------------------
__global__ __launch_bounds__(256) void radix_select_kernel(
    const float* __restrict__ data, int count, int k, int stride,
    float* __restrict__ out)
{
  const float* seg = data + (size_t)blockIdx.x * stride;
  __shared__ unsigned int hist[256];
  __shared__ unsigned int prefix_s;
  __shared__ int k_s;
  unsigned int prefix = 0u;
  int kk = k;
  for (int pass = 3; pass >= 0; --pass) {
    const int shift = pass * 8;
    hist[threadIdx.x] = 0u;
    __syncthreads();
    const unsigned int mask_known =
        (pass == 3) ? 0u : (0xFFFFFFFFu << ((pass + 1) * 8));
    for (int i = threadIdx.x; i < count; i += 256) {
      const unsigned int bits = __float_as_uint(seg[i]);
      if ((bits & mask_known) == prefix)
        atomicAdd(&hist[(bits >> shift) & 0xFFu], 1u);
    }
    __syncthreads();
    if (threadIdx.x == 0) {
      int rem = kk;
      unsigned int d = 0;
      for (; d < 256u; ++d) {
        if (rem < (int)hist[d]) break;
        rem -= (int)hist[d];
      }
      prefix_s = prefix | (d << shift);
      k_s = rem;
    }
    __syncthreads();
    prefix = prefix_s;
    kk = k_s;
    __syncthreads();
  }
  if (threadIdx.x == 0) out[blockIdx.x] = __uint_as_float(prefix);
}

__global__ __launch_bounds__(256) void threshold_kernel(
    float* __restrict__ a, const float* __restrict__ sig, int total, int seglen)
{
  const int idx = blockIdx.x * 256 + threadIdx.x;
  if (idx >= total) return;
  const float v = a[idx];
  if (v < sig[idx / seglen]) a[idx] = 0.0f;
}

// ---------------------------------------------------------------------------
// attn @ v : v bf16 [M1P x 768]; out bf16 (B,N,C)
// ---------------------------------------------------------------------------
__global__ __launch_bounds__(256) void attn_v_kernel(
    const float* __restrict__ attn, const __bf16* __restrict__ v,
    __bf16* __restrict__ out)
{
  const int bh = blockIdx.x;
  const int b = bh / H_, h = bh % H_;
  __shared__ float Vs[N_ * HD_];
  for (int idx = threadIdx.x; idx < N_ * HD_; idx += 256) {
    const int j = idx / HD_, d = idx % HD_;
    Vs[idx] = (float)v[((size_t)(b * N_ + j)) * C_ + h * HD_ + d];
  }
  __syncthreads();
  const int rg = threadIdx.x >> 6, d = threadIdx.x & 63;
  const float* abase = attn + (size_t)bh * N_ * N_;
  for (int n = rg; n < N_; n += 4) {
    const float* ar = abase + (size_t)n * N_;
    float acc = 0.f;
    for (int j = 0; j < N_; ++j) acc += ar[j] * Vs[j * HD_ + d];
    out[((size_t)b * N_ + n) * C_ + h * HD_ + d] = (__bf16)acc;
  }
}

// ---------------------------------------------------------------------------
// token_rank, stable descending argsort, w gather, x_prop (as round 2)
// ---------------------------------------------------------------------------
__global__ __launch_bounds__(256) void token_rank_kernel(
    const float* __restrict__ attn, float* __restrict__ tr)
{
  const int b = blockIdx.x;
  for (int j = threadIdx.x; j < N1_; j += 256) {
    const int n = j + 1;
    float s = 0.f;
    #pragma unroll
    for (int h = 0; h < H_; ++h)
      s += attn[(((size_t)(b * H_ + h)) * N_ + n) * N_ + n];
    tr[b * N1_ + j] = s * (1.f / H_);
  }
}

__global__ __launch_bounds__(256) void order_kernel(
    const float* __restrict__ tr, int* __restrict__ order)
{
  const int b = blockIdx.x;
  __shared__ float v[N1_];
  const int t = threadIdx.x;
  if (t < N1_) v[t] = tr[b * N1_ + t];
  __syncthreads();
  if (t < N1_) {
    const float mv = v[t];
    int r = 0;
    for (int i = 0; i < N1_; ++i) {
      const float vi = v[i];
      r += (vi > mv) || (vi == mv && i < t);
    }
    order[b * N1_ + r] = t;
  }
}

__global__ __launch_bounds__(256) void w_gather_kernel(
    const float* __restrict__ attn, const int* __restrict__ ord,
    float* __restrict__ w)
{
  const int idx = blockIdx.x * 256 + threadIdx.x;
  if (idx >= B_ * H_ * NK_ * NP_) return;
  const int e = idx % NP_;
  const int k = (idx / NP_) % NK_;
  const int h = (idx / (NP_ * NK_)) % H_;
  const int b = idx / (NP_ * NK_ * H_);
  const int ki = ord[b * N1_ + k] + 1;
  const int ej = ord[b * N1_ + NK_ + e] + 1;
  w[idx] = attn[(((size_t)b * H_ + h) * N_ + ki) * N_ + ej];
}

__global__ __launch_bounds__(256) void xprop_kernel(
    const float* __restrict__ x1, const float* __restrict__ w,
    const int* __restrict__ ord, float* __restrict__ x2)
{
  const int b = blockIdx.y;
  const int kk = blockIdx.x;   // 0..156
  const int t = threadIdx.x;
  if (kk == 0) {
    for (int c = t; c < C_; c += 256)
      x2[(size_t)b * N2_ * C_ + c] = x1[(size_t)b * N_ * C_ + c];
    return;
  }
  const int k = kk - 1;
  __shared__ float ws_[H_ * NP_];
  __shared__ int es[NP_];
  if (t < NP_) es[t] = ord[b * N1_ + NK_ + t] + 1;
  for (int i = t; i < H_ * NP_; i += 256) {
    const int h = i / NP_, e = i % NP_;
    ws_[i] = w[(((size_t)b * H_ + h) * NK_ + k) * NP_ + e];
  }
  __syncthreads();
  const int kept = ord[b * N1_ + k] + 1;
  const float* xk = x1 + ((size_t)b * N_ + kept) * C_;
  float* xo = x2 + ((size_t)b * N2_ + 1 + k) * C_;
  for (int c = t; c < C_; c += 256) {
    const int h = c >> 6;
    float acc = 0.f;
    #pragma unroll 8
    for (int e = 0; e < NP_; ++e)
      acc += ws_[h * NP_ + e] * x1[((size_t)b * N_ + es[e]) * C_ + c];
    xo[c] = xk[c] + ALPHA_ * acc;
  }
}

// ---------------------------------------------------------------------------
// Launcher
// ---------------------------------------------------------------------------
extern "C" void kernel_launch(void* const* d_in, const int* in_sizes, int n_in,
                              void* d_out, int out_size, void* d_ws, size_t ws_size,
                              hipStream_t stream)
{
  const float* x     = (const float*)d_in[0];
  const float* n1w   = (const float*)d_in[1];
  const float* n1b   = (const float*)d_in[2];
  const float* qkvw  = (const float*)d_in[3];
  const float* projw = (const float*)d_in[4];
  const float* projb = (const float*)d_in[5];
  const float* n2w   = (const float*)d_in[6];
  const float* n2b   = (const float*)d_in[7];
  const float* fc1w  = (const float*)d_in[8];
  const float* fc1b  = (const float*)d_in[9];
  const float* fc2w  = (const float*)d_in[10];
  const float* fc2b  = (const float*)d_in[11];
  float* outp = (float*)d_out;

  char* ws = (char*)d_ws;
  __bf16* xa_hi = (__bf16*)(ws + OFFB_XAHI);
  __bf16* xa_lo = (__bf16*)(ws + OFFB_XALO);
  float*  attn  = (float*)(ws + OFFB_ATTN);
  __bf16* fc1h  = (__bf16*)(ws + OFFB_FC1H);
  __bf16* h2    = (__bf16*)(ws + OFFB_H2);
  __bf16* fc1wb = (__bf16*)(ws + OFFB_FC1W);
  __bf16* fc2wb = (__bf16*)(ws + OFFB_FC2W);
  float*  qk    = (float*)(ws + OFFB_QK);
  __bf16* vb    = (__bf16*)(ws + OFFB_VB);
  float*  x1    = (float*)(ws + OFFB_X1);
  __bf16* aout  = (__bf16*)(ws + OFFB_AOUT);
  float*  wbuf  = (float*)(ws + OFFB_WBUF);
  __bf16* qwhi  = (__bf16*)(ws + OFFB_QWHI);
  __bf16* qwlo  = (__bf16*)(ws + OFFB_QWLO);
  __bf16* prjwb = (__bf16*)(ws + OFFB_PRJW);
  float*  sig   = (float*)(ws + OFFB_SIG);
  float*  wsig  = (float*)(ws + OFFB_WSIG);
  float*  tr    = (float*)(ws + OFFB_TR);
  int*    ord   = (int*)(ws + OFFB_ORD);
  float*  x2    = outp;

  // Weight conversions needed early
  wsplit_kernel<<<(2304 * 768 + 255) / 256, 256, 0, stream>>>(
      qkvw, qwhi, qwlo, 2304 * 768);
  wconv_kernel<<<(768 * 768 + 255) / 256, 256, 0, stream>>>(
      projw, prjwb, 768 * 768);
  // 1. LN1 -> split bf16 (pad rows zeroed)
  ln_bf16_kernel<<<M1P_, 256, 0, stream>>>(x, n1w, n1b, xa_hi, xa_lo, M1_);
  // 2a. qk = split GEMM, N=1536 (fp32-grade: ordering-critical path)
  gemm_split_kernel<<<dim3(1536 / 128, M1P_ / 128), 256, 0, stream>>>(
      xa_hi, xa_lo, qwhi, qwlo, qk, 1536, C_);
  // 2b. v = plain bf16 GEMM, N=768 -> bf16
  gemm_bf16_kernel<<<dim3(C_ / 128, M1P_ / 128), 256, 0, stream>>>(
      xa_hi, qwhi + (size_t)1536 * C_, nullptr, nullptr, nullptr, vb,
      M1P_, C_, C_, 0);
  // 3. scores (attn overwrites xa region; xa dead)
  attn_scores_kernel<<<B_ * H_, 256, 0, stream>>>(qk, attn);
  // 4. softmax
  softmax_kernel<<<(B_ * H_ * N_) / 4, 256, 0, stream>>>(attn);
  // 5. sigma + threshold
  radix_select_kernel<<<B_ * H_, 256, 0, stream>>>(attn, N_ * N_, KASC_ATTN,
                                                   N_ * N_, sig);
  {
    const int total = B_ * H_ * N_ * N_;
    threshold_kernel<<<(total + 255) / 256, 256, 0, stream>>>(attn, sig, total,
                                                              N_ * N_);
  }
  // 6. attn @ v -> aout (bf16)
  attn_v_kernel<<<B_ * H_, 256, 0, stream>>>(attn, vb, aout);
  // 7. token_rank + stable order
  token_rank_kernel<<<B_, 256, 0, stream>>>(attn, tr);
  order_kernel<<<B_, 256, 0, stream>>>(tr, ord);
  // 8. x1 = x + aout @ proj_w.T + proj_b (fp32; pad rows skipped)
  gemm_bf16_kernel<<<dim3(C_ / 128, M1P_ / 128), 256, 0, stream>>>(
      aout, prjwb, projb, x, x1, nullptr, M1_, C_, C_, 0);
  // 9. w gather + w_sigma + threshold
  {
    const int total = B_ * H_ * NK_ * NP_;
    w_gather_kernel<<<(total + 255) / 256, 256, 0, stream>>>(attn, ord, wbuf);
    radix_select_kernel<<<B_ * H_, 256, 0, stream>>>(wbuf, NK_ * NP_, KASC_W,
                                                     NK_ * NP_, wsig);
    threshold_kernel<<<(total + 255) / 256, 256, 0, stream>>>(wbuf, wsig, total,
                                                              NK_ * NP_);
  }
  // attn now dead -> convert fc1/fc2 weights into tail of region A
  wconv_kernel<<<(MLP_ * C_ + 255) / 256, 256, 0, stream>>>(
      fc1w, fc1wb, MLP_ * C_);
  wconv_kernel<<<(C_ * MLP_ + 255) / 256, 256, 0, stream>>>(
      fc2w, fc2wb, C_ * MLP_);
  // 10. x_prop + assemble x2 (d_out)
  xprop_kernel<<<dim3(N2_, B_), 256, 0, stream>>>(x1, wbuf, ord, x2);
  // 11. LN2 -> bf16 (pad rows zeroed)
  ln_bf16_kernel<<<M2P_, 256, 0, stream>>>(x2, n2w, n2b, h2, nullptr, M2_);
  // 12. fc1 + bias + gelu -> bf16
  gemm_bf16_kernel<<<dim3(MLP_ / 128, M2P_ / 128), 256, 0, stream>>>(
      h2, fc1wb, fc1b, nullptr, nullptr, fc1h, M2P_, MLP_, C_, 1);
  // 13. out = x2 + fc1h @ fc2_w.T + fc2_b (in-place on d_out; rows < M2)
  gemm_bf16_kernel<<<dim3(C_ / 128, M2P_ / 128), 256, 0, stream>>>(
      fc1h, fc2wb, fc2b, x2, outp, nullptr, M2_, C_, MLP_, 0);
}

// Round 4
// 1366.643 us; speedup vs baseline: 2.9304x; 1.4816x over previous
//
#include <hip/hip_runtime.h>
#include <math.h>

// ---------------------------------------------------------------------------
// Problem constants
// ---------------------------------------------------------------------------
constexpr int B_  = 64;
constexpr int N_  = 197;
constexpr int C_  = 768;
constexpr int H_  = 12;
constexpr int HD_ = 64;
constexpr int NP_ = 40;
constexpr int NK_ = 156;
constexpr int N1_ = 196;
constexpr int N2_ = 157;
constexpr int MLP_ = 3072;
constexpr int M1_ = B_ * N_;    // 12608
constexpr int M2_ = B_ * N2_;   // 10048
constexpr int M1P_ = 12672;     // pad to 128
constexpr int M2P_ = 10112;     // pad to 128
constexpr float SCALE_ = 0.125f;
constexpr float ALPHA_ = 0.1f;
constexpr float EPS_   = 1e-5f;
constexpr int KASC_ATTN = N_ * N_ - 1 - 29106;   // 9702
constexpr int KASC_W    = NK_ * NP_ - 1 - 312;   // 5927

typedef __bf16 bf16x8 __attribute__((ext_vector_type(8)));
typedef float  floatx4 __attribute__((ext_vector_type(4)));

// ---------------------------------------------------------------------------
// Workspace layout (byte offsets) — identical envelope to round 3 (~224.9 MB,
// proven to fit). qk region now holds q/k hi+lo bf16 (same total bytes).
// ---------------------------------------------------------------------------
constexpr size_t A_B     = 0;
constexpr size_t OFFB_XAHI = A_B;                        // bf16 M1P*C
constexpr size_t OFFB_XALO = A_B + 19464192;             // bf16 M1P*C
constexpr size_t OFFB_ATTN = A_B;                        // fp32 768*197*197
constexpr size_t OFFB_FC1H = A_B;                        // bf16 M2P*3072
constexpr size_t OFFB_H2   = A_B + 62128128;             // bf16 M2P*768
constexpr size_t OFFB_FC1W = A_B + 77660160;             // bf16 3072*768
constexpr size_t OFFB_FC2W = A_B + 82378752;             // bf16 768*3072
constexpr size_t B_B     = 119221248;
constexpr size_t OFFB_QHI  = B_B;                        // bf16 M1P*1536
constexpr size_t OFFB_QLO  = B_B + 38928384;             // bf16 M1P*1536
constexpr size_t OFFB_VB   = B_B + 77856768;             // bf16 M1P*768
constexpr size_t OFFB_X1   = B_B;                        // fp32 M1P*768
constexpr size_t OFFB_AOUT = B_B + 38928384;             // bf16 M1P*768
constexpr size_t OFFB_WBUF = B_B + 77856768;             // fp32 768*156*40
constexpr size_t W_B     = 216542208;
constexpr size_t OFFB_QWHI = W_B;                        // bf16 2304*768
constexpr size_t OFFB_QWLO = W_B + 3538944;
constexpr size_t OFFB_PRJW = W_B + 7077888;              // bf16 768*768
constexpr size_t S_B     = 224799744;
constexpr size_t OFFB_SIG  = S_B;
constexpr size_t OFFB_WSIG = S_B + 3072;
constexpr size_t OFFB_TR   = S_B + 6144;
constexpr size_t OFFB_ORD  = S_B + 56320;

// ---------------------------------------------------------------------------
// Weight conversion kernels
// ---------------------------------------------------------------------------
__global__ __launch_bounds__(256) void wsplit_kernel(
    const float* __restrict__ w, __bf16* __restrict__ hi,
    __bf16* __restrict__ lo, int n)
{
  const int i = blockIdx.x * 256 + threadIdx.x;
  if (i >= n) return;
  const float v = w[i];
  const __bf16 h = (__bf16)v;
  hi[i] = h;
  lo[i] = (__bf16)(v - (float)h);
}

__global__ __launch_bounds__(256) void wconv_kernel(
    const float* __restrict__ w, __bf16* __restrict__ o, int n)
{
  const int i = blockIdx.x * 256 + threadIdx.x;
  if (i < n) o[i] = (__bf16)w[i];
}

// ---------------------------------------------------------------------------
// Helpers
// ---------------------------------------------------------------------------
__device__ __forceinline__ float block_reduce_sum(float v, float* red) {
  #pragma unroll
  for (int off = 32; off; off >>= 1) v += __shfl_xor(v, off);
  if ((threadIdx.x & 63) == 0) red[threadIdx.x >> 6] = v;
  __syncthreads();
  float r = red[0] + red[1] + red[2] + red[3];
  __syncthreads();
  return r;
}

// ---------------------------------------------------------------------------
// LayerNorm -> bf16 (optionally split hi/lo). Pad rows (>= Mvalid) -> zeros.
// ---------------------------------------------------------------------------
__global__ __launch_bounds__(256) void ln_bf16_kernel(
    const float* __restrict__ x, const float* __restrict__ w,
    const float* __restrict__ b, __bf16* __restrict__ ohi,
    __bf16* __restrict__ olo, int Mvalid)
{
  __shared__ float red[4];
  const size_t row = blockIdx.x;
  const int t = threadIdx.x;
  if ((int)row >= Mvalid) {
    #pragma unroll
    for (int i = 0; i < 3; ++i) {
      ohi[row * C_ + t + 256 * i] = (__bf16)0.f;
      if (olo) olo[row * C_ + t + 256 * i] = (__bf16)0.f;
    }
    return;
  }
  const float* xr = x + row * C_;
  float v[3];
  float s = 0.f;
  #pragma unroll
  for (int i = 0; i < 3; ++i) { v[i] = xr[t + 256 * i]; s += v[i]; }
  const float mu = block_reduce_sum(s, red) * (1.f / 768.f);
  s = 0.f;
  #pragma unroll
  for (int i = 0; i < 3; ++i) { float d = v[i] - mu; s += d * d; }
  const float var = block_reduce_sum(s, red) * (1.f / 768.f);
  const float rs = rsqrtf(var + EPS_);
  #pragma unroll
  for (int i = 0; i < 3; ++i) {
    const int c = t + 256 * i;
    const float val = (v[i] - mu) * rs * w[c] + b[c];
    const __bf16 h = (__bf16)val;
    ohi[row * C_ + c] = h;
    if (olo) olo[row * C_ + c] = (__bf16)(val - (float)h);
  }
}

// ---------------------------------------------------------------------------
// MFMA tile staging: 128x32 bf16 tile, global -> LDS via global_load_lds x16B
// ---------------------------------------------------------------------------
__device__ __forceinline__ void stage_tile(
    const __bf16* __restrict__ gbase, int ldg, __bf16* lds, int wave, int lane)
{
  #pragma unroll
  for (int j = 0; j < 2; ++j) {
    const int seg = 4 * j + wave;
    const int row = seg * 16 + (lane >> 2);
    const int col = (lane & 3) * 8;
    const __bf16* g = gbase + (size_t)row * ldg + col;
    __bf16* l = lds + seg * 512 + lane * 8;
    __builtin_amdgcn_global_load_lds(
        (const __attribute__((address_space(1))) unsigned int*)g,
        (__attribute__((address_space(3))) unsigned int*)l, 16, 0, 0);
  }
}

__device__ __forceinline__ bf16x8 frag(const __bf16* lds, int r, int hi8) {
  return *(const bf16x8*)(lds + r * 32 + hi8);
}

// ---------------------------------------------------------------------------
// Plain bf16 MFMA GEMM: C[m,n] = sum_k A[m,k]*Bw[n,k] (+bias,+gelu,+res)
// ---------------------------------------------------------------------------
__global__ __launch_bounds__(256) void gemm_bf16_kernel(
    const __bf16* __restrict__ A, const __bf16* __restrict__ Bw,
    const float* __restrict__ bias, const float* __restrict__ res,
    float* __restrict__ outf, __bf16* __restrict__ outb,
    int Mstore, int Nn, int K, int act)
{
  __shared__ __bf16 As[128 * 32];
  __shared__ __bf16 Bs[128 * 32];
  const int t = threadIdx.x;
  const int wave = t >> 6, lane = t & 63;
  const int m0 = blockIdx.y * 128, n0 = blockIdx.x * 128;
  const int wm = (wave >> 1) * 64, wn = (wave & 1) * 64;
  const int lo = lane & 15, hi8 = (lane >> 4) * 8;
  floatx4 acc[4][4] = {};
  for (int k0 = 0; k0 < K; k0 += 32) {
    stage_tile(A + (size_t)m0 * K + k0, K, As, wave, lane);
    stage_tile(Bw + (size_t)n0 * K + k0, K, Bs, wave, lane);
    __syncthreads();
    bf16x8 af[4], bfr[4];
    #pragma unroll
    for (int i = 0; i < 4; ++i) af[i]  = frag(As, wm + i * 16 + lo, hi8);
    #pragma unroll
    for (int j = 0; j < 4; ++j) bfr[j] = frag(Bs, wn + j * 16 + lo, hi8);
    #pragma unroll
    for (int i = 0; i < 4; ++i)
      #pragma unroll
      for (int j = 0; j < 4; ++j)
        acc[i][j] = __builtin_amdgcn_mfma_f32_16x16x32_bf16(
            af[i], bfr[j], acc[i][j], 0, 0, 0);
    __syncthreads();
  }
  #pragma unroll
  for (int i = 0; i < 4; ++i) {
    #pragma unroll
    for (int j = 0; j < 4; ++j) {
      #pragma unroll
      for (int r = 0; r < 4; ++r) {
        const int m = m0 + wm + i * 16 + (lane >> 4) * 4 + r;
        const int n = n0 + wn + j * 16 + lo;
        if (m < Mstore) {
          float v = acc[i][j][r];
          if (bias) v += bias[n];
          if (act) v = 0.5f * v * (1.0f + erff(v * 0.7071067811865476f));
          if (res) v += res[(size_t)m * Nn + n];
          if (outf) outf[(size_t)m * Nn + n] = v;
          else      outb[(size_t)m * Nn + n] = (__bf16)v;
        }
      }
    }
  }
}

// ---------------------------------------------------------------------------
// Split-bf16 MFMA GEMM: acc = Ah*Bh + Ah*Bl + Al*Bh; output split hi/lo bf16.
// Used for q,k (ordering-critical path feeds scores MFMA downstream).
// ---------------------------------------------------------------------------
__global__ __launch_bounds__(256) void gemm_split_kernel(
    const __bf16* __restrict__ Ah, const __bf16* __restrict__ Al,
    const __bf16* __restrict__ Bh, const __bf16* __restrict__ Bl,
    __bf16* __restrict__ outhi, __bf16* __restrict__ outlo, int Nn, int K)
{
  __shared__ __bf16 Ahs[128 * 32];
  __shared__ __bf16 Als[128 * 32];
  __shared__ __bf16 Bhs[128 * 32];
  __shared__ __bf16 Bls[128 * 32];
  const int t = threadIdx.x;
  const int wave = t >> 6, lane = t & 63;
  const int m0 = blockIdx.y * 128, n0 = blockIdx.x * 128;
  const int wm = (wave >> 1) * 64, wn = (wave & 1) * 64;
  const int lo = lane & 15, hi8 = (lane >> 4) * 8;
  floatx4 acc[4][4] = {};
  for (int k0 = 0; k0 < K; k0 += 32) {
    stage_tile(Ah + (size_t)m0 * K + k0, K, Ahs, wave, lane);
    stage_tile(Al + (size_t)m0 * K + k0, K, Als, wave, lane);
    stage_tile(Bh + (size_t)n0 * K + k0, K, Bhs, wave, lane);
    stage_tile(Bl + (size_t)n0 * K + k0, K, Bls, wave, lane);
    __syncthreads();
    bf16x8 ah[4], al[4], bh[4], bl[4];
    #pragma unroll
    for (int i = 0; i < 4; ++i) {
      ah[i] = frag(Ahs, wm + i * 16 + lo, hi8);
      al[i] = frag(Als, wm + i * 16 + lo, hi8);
    }
    #pragma unroll
    for (int j = 0; j < 4; ++j) {
      bh[j] = frag(Bhs, wn + j * 16 + lo, hi8);
      bl[j] = frag(Bls, wn + j * 16 + lo, hi8);
    }
    #pragma unroll
    for (int i = 0; i < 4; ++i)
      #pragma unroll
      for (int j = 0; j < 4; ++j) {
        acc[i][j] = __builtin_amdgcn_mfma_f32_16x16x32_bf16(
            ah[i], bh[j], acc[i][j], 0, 0, 0);
        acc[i][j] = __builtin_amdgcn_mfma_f32_16x16x32_bf16(
            ah[i], bl[j], acc[i][j], 0, 0, 0);
        acc[i][j] = __builtin_amdgcn_mfma_f32_16x16x32_bf16(
            al[i], bh[j], acc[i][j], 0, 0, 0);
      }
    __syncthreads();
  }
  #pragma unroll
  for (int i = 0; i < 4; ++i)
    #pragma unroll
    for (int j = 0; j < 4; ++j)
      #pragma unroll
      for (int r = 0; r < 4; ++r) {
        const int m = m0 + wm + i * 16 + (lane >> 4) * 4 + r;
        const int n = n0 + wn + j * 16 + lo;
        const float v = acc[i][j][r];
        const __bf16 h = (__bf16)v;
        outhi[(size_t)m * Nn + n] = h;
        outlo[(size_t)m * Nn + n] = (__bf16)(v - (float)h);
      }
}

// ---------------------------------------------------------------------------
// Scores via split-bf16 MFMA: per (b,h), S = scale * (Qhi+Qlo)(Khi+Klo)^T.
// Q frags from global; K staged in LDS (72-padded rows, conflict-free b128).
// ---------------------------------------------------------------------------
__global__ __launch_bounds__(256) void scores_mfma_kernel(
    const __bf16* __restrict__ qhi, const __bf16* __restrict__ qlo,
    float* __restrict__ attn)
{
  const int bh = blockIdx.x;
  const int b = bh / H_, h = bh % H_;
  __shared__ __bf16 Khi[208 * 72];
  __shared__ __bf16 Klo[208 * 72];
  const int t = threadIdx.x;
  // stage K (cols 768.. of q/k buffer), rows >=197 zeroed
  for (int idx = t; idx < 208 * 32; idx += 256) {
    const int j = idx >> 5;
    const int c2 = (idx & 31) * 2;
    unsigned int vh = 0u, vl = 0u;
    if (j < N_) {
      const size_t g = ((size_t)(b * N_ + j)) * 1536 + 768 + h * HD_ + c2;
      vh = *(const unsigned int*)(qhi + g);
      vl = *(const unsigned int*)(qlo + g);
    }
    *(unsigned int*)(Khi + j * 72 + c2) = vh;
    *(unsigned int*)(Klo + j * 72 + c2) = vl;
  }
  __syncthreads();
  const int wave = t >> 6, lane = t & 63;
  const int lo16 = lane & 15, k8 = (lane >> 4) * 8;
  float* Sbh = attn + (size_t)bh * N_ * N_;
  bf16x8 zf;
  #pragma unroll
  for (int e = 0; e < 8; ++e) zf[e] = (__bf16)0.f;
  for (int i = 0; i < 4; ++i) {
    const int mrow = wave * 64 + i * 16 + lo16;
    bf16x8 ahi[2], alo[2];
    #pragma unroll
    for (int kk = 0; kk < 2; ++kk) {
      if (mrow < N_) {
        const size_t g = ((size_t)(b * N_ + mrow)) * 1536 + h * HD_ + kk * 32 + k8;
        ahi[kk] = *(const bf16x8*)(qhi + g);
        alo[kk] = *(const bf16x8*)(qlo + g);
      } else {
        ahi[kk] = zf;
        alo[kk] = zf;
      }
    }
    for (int j = 0; j < 13; ++j) {
      floatx4 acc = {0.f, 0.f, 0.f, 0.f};
      #pragma unroll
      for (int kk = 0; kk < 2; ++kk) {
        const bf16x8 bh_ = *(const bf16x8*)(Khi + (j * 16 + lo16) * 72 + kk * 32 + k8);
        const bf16x8 bl_ = *(const bf16x8*)(Klo + (j * 16 + lo16) * 72 + kk * 32 + k8);
        acc = __builtin_amdgcn_mfma_f32_16x16x32_bf16(ahi[kk], bh_, acc, 0, 0, 0);
        acc = __builtin_amdgcn_mfma_f32_16x16x32_bf16(ahi[kk], bl_, acc, 0, 0, 0);
        acc = __builtin_amdgcn_mfma_f32_16x16x32_bf16(alo[kk], bh_, acc, 0, 0, 0);
        acc = __builtin_amdgcn_mfma_f32_16x16x32_bf16(alo[kk], bl_, acc, 0, 0, 0);
      }
      const int col = j * 16 + lo16;
      if (col < N_) {
        #pragma unroll
        for (int r = 0; r < 4; ++r) {
          const int row = wave * 64 + i * 16 + (lane >> 4) * 4 + r;
          if (row < N_) Sbh[(size_t)row * N_ + col] = acc[r] * SCALE_;
        }
      }
    }
  }
}

// ---------------------------------------------------------------------------
// Softmax along last dim (197). One wave per row, 4 rows per block.
// ---------------------------------------------------------------------------
__global__ __launch_bounds__(256) void softmax_kernel(float* __restrict__ attn)
{
  const int row = blockIdx.x * 4 + (threadIdx.x >> 6);
  const int lane = threadIdx.x & 63;
  float* r = attn + (size_t)row * N_;
  float vals[4];
  float m = -1e30f;
  int cnt = 0;
  for (int j = lane; j < N_; j += 64) { vals[cnt] = r[j]; m = fmaxf(m, vals[cnt]); ++cnt; }
  #pragma unroll
  for (int off = 32; off; off >>= 1) m = fmaxf(m, __shfl_xor(m, off));
  float s = 0.f;
  for (int i = 0; i < cnt; ++i) { vals[i] = expf(vals[i] - m); s += vals[i]; }
  #pragma unroll
  for (int off = 32; off; off >>= 1) s += __shfl_xor(s, off);
  const float inv = 1.0f / s;
  cnt = 0;
  for (int j = lane; j < N_; j += 64) { r[j] = vals[cnt] * inv; ++cnt; }
}

// ---------------------------------------------------------------------------
// Radix select: per-segment k-th smallest (ascending) of non-negative floats.
// ---------------------------------------------------------------------------
__global__ __launch_bounds__(256) void radix_select_kernel(
    const float* __restrict__ data, int count, int k, int stride,
    float* __restrict__ out)
{
  const float* seg = data + (size_t)blockIdx.x * stride;
  __shared__ unsigned int hist[256];
  __shared__ unsigned int prefix_s;
  __shared__ int k_s;
  unsigned int prefix = 0u;
  int kk = k;
  for (int pass = 3; pass >= 0; --pass) {
    const int shift = pass * 8;
    hist[threadIdx.x] = 0u;
    __syncthreads();
    const unsigned int mask_known =
        (pass == 3) ? 0u : (0xFFFFFFFFu << ((pass + 1) * 8));
    for (int i = threadIdx.x; i < count; i += 256) {
      const unsigned int bits = __float_as_uint(seg[i]);
      if ((bits & mask_known) == prefix)
        atomicAdd(&hist[(bits >> shift) & 0xFFu], 1u);
    }
    __syncthreads();
    if (threadIdx.x == 0) {
      int rem = kk;
      unsigned int d = 0;
      for (; d < 256u; ++d) {
        if (rem < (int)hist[d]) break;
        rem -= (int)hist[d];
      }
      prefix_s = prefix | (d << shift);
      k_s = rem;
    }
    __syncthreads();
    prefix = prefix_s;
    kk = k_s;
    __syncthreads();
  }
  if (threadIdx.x == 0) out[blockIdx.x] = __uint_as_float(prefix);
}

__global__ __launch_bounds__(256) void threshold_kernel(
    float* __restrict__ a, const float* __restrict__ sig, int total, int seglen)
{
  const int idx = blockIdx.x * 256 + threadIdx.x;
  if (idx >= total) return;
  const float v = a[idx];
  if (v < sig[idx / seglen]) a[idx] = 0.0f;
}

// ---------------------------------------------------------------------------
// attn @ v via bf16 MFMA. Threshold applied during P staging.
// grid (bh, mt): 64-row m-tile per workgroup. LDS 232-padded (conflict-free).
// ---------------------------------------------------------------------------
__global__ __launch_bounds__(256) void attn_v_mfma_kernel(
    const float* __restrict__ attn, const float* __restrict__ sig,
    const __bf16* __restrict__ v, __bf16* __restrict__ out)
{
  const int bh = blockIdx.x;
  const int mt = blockIdx.y;     // rows mt*64 .. mt*64+63
  const int b = bh / H_, h = bh % H_;
  __shared__ __bf16 Ps[64 * 232];
  __shared__ __bf16 Vt[64 * 232];
  const int t = threadIdx.x;
  const float sigbh = sig[bh];
  const float* abase = attn + (size_t)bh * N_ * N_;
  // stage P (thresholded, bf16), zero pads. dword-pair granularity.
  for (int idx = t; idx < 64 * 112; idx += 256) {
    const int r = idx / 112;
    const int j0 = (idx % 112) * 2;
    const int gr = mt * 64 + r;
    float v0 = 0.f, v1 = 0.f;
    if (gr < N_) {
      if (j0 < N_)     { const float a0 = abase[(size_t)gr * N_ + j0];     v0 = (a0 >= sigbh) ? a0 : 0.f; }
      if (j0 + 1 < N_) { const float a1 = abase[(size_t)gr * N_ + j0 + 1]; v1 = (a1 >= sigbh) ? a1 : 0.f; }
    }
    __bf16 p2[2] = {(__bf16)v0, (__bf16)v1};
    *(unsigned int*)(Ps + r * 232 + j0) = *(unsigned int*)p2;
  }
  // stage V^T: Vt[d][j] = v[b,j,h,d]; zero pads j in [197,224)
  for (int idx = t; idx < 64 * 224; idx += 256) {
    const int d = idx / 224;
    const int j = idx % 224;
    __bf16 val = (__bf16)0.f;
    if (j < N_) val = v[((size_t)(b * N_ + j)) * C_ + h * HD_ + d];
    Vt[d * 232 + j] = val;
  }
  __syncthreads();
  const int wave = t >> 6, lane = t & 63;
  const int lo16 = lane & 15, k8 = (lane >> 4) * 8;
  #pragma unroll
  for (int jn = 0; jn < 4; ++jn) {
    floatx4 acc = {0.f, 0.f, 0.f, 0.f};
    #pragma unroll
    for (int kk = 0; kk < 7; ++kk) {
      const bf16x8 a = *(const bf16x8*)(Ps + (wave * 16 + lo16) * 232 + kk * 32 + k8);
      const bf16x8 bb = *(const bf16x8*)(Vt + (jn * 16 + lo16) * 232 + kk * 32 + k8);
      acc = __builtin_amdgcn_mfma_f32_16x16x32_bf16(a, bb, acc, 0, 0, 0);
    }
    const int d = jn * 16 + lo16;
    #pragma unroll
    for (int r = 0; r < 4; ++r) {
      const int m = mt * 64 + wave * 16 + (lane >> 4) * 4 + r;
      if (m < N_)
        out[((size_t)b * N_ + m) * C_ + h * HD_ + d] = (__bf16)acc[r];
    }
  }
}

// ---------------------------------------------------------------------------
// token_rank[b,j] = mean_h thresh(attn[b,h,j+1,j+1])
// ---------------------------------------------------------------------------
__global__ __launch_bounds__(256) void token_rank_kernel(
    const float* __restrict__ attn, const float* __restrict__ sig,
    float* __restrict__ tr)
{
  const int b = blockIdx.x;
  for (int j = threadIdx.x; j < N1_; j += 256) {
    const int n = j + 1;
    float s = 0.f;
    #pragma unroll
    for (int h = 0; h < H_; ++h) {
      const float d = attn[(((size_t)(b * H_ + h)) * N_ + n) * N_ + n];
      s += (d >= sig[b * H_ + h]) ? d : 0.f;
    }
    tr[b * N1_ + j] = s * (1.f / H_);
  }
}

__global__ __launch_bounds__(256) void order_kernel(
    const float* __restrict__ tr, int* __restrict__ order)
{
  const int b = blockIdx.x;
  __shared__ float v[N1_];
  const int t = threadIdx.x;
  if (t < N1_) v[t] = tr[b * N1_ + t];
  __syncthreads();
  if (t < N1_) {
    const float mv = v[t];
    int r = 0;
    for (int i = 0; i < N1_; ++i) {
      const float vi = v[i];
      r += (vi > mv) || (vi == mv && i < t);
    }
    order[b * N1_ + r] = t;
  }
}

__global__ __launch_bounds__(256) void w_gather_kernel(
    const float* __restrict__ attn, const float* __restrict__ sig,
    const int* __restrict__ ord, float* __restrict__ w)
{
  const int idx = blockIdx.x * 256 + threadIdx.x;
  if (idx >= B_ * H_ * NK_ * NP_) return;
  const int e = idx % NP_;
  const int k = (idx / NP_) % NK_;
  const int h = (idx / (NP_ * NK_)) % H_;
  const int b = idx / (NP_ * NK_ * H_);
  const int ki = ord[b * N1_ + k] + 1;
  const int ej = ord[b * N1_ + NK_ + e] + 1;
  const float v = attn[(((size_t)b * H_ + h) * N_ + ki) * N_ + ej];
  w[idx] = (v >= sig[b * H_ + h]) ? v : 0.f;
}

__global__ __launch_bounds__(256) void xprop_kernel(
    const float* __restrict__ x1, const float* __restrict__ w,
    const int* __restrict__ ord, float* __restrict__ x2)
{
  const int b = blockIdx.y;
  const int kk = blockIdx.x;   // 0..156
  const int t = threadIdx.x;
  if (kk == 0) {
    for (int c = t; c < C_; c += 256)
      x2[(size_t)b * N2_ * C_ + c] = x1[(size_t)b * N_ * C_ + c];
    return;
  }
  const int k = kk - 1;
  __shared__ float ws_[H_ * NP_];
  __shared__ int es[NP_];
  if (t < NP_) es[t] = ord[b * N1_ + NK_ + t] + 1;
  for (int i = t; i < H_ * NP_; i += 256) {
    const int h = i / NP_, e = i % NP_;
    ws_[i] = w[(((size_t)b * H_ + h) * NK_ + k) * NP_ + e];
  }
  __syncthreads();
  const int kept = ord[b * N1_ + k] + 1;
  const float* xk = x1 + ((size_t)b * N_ + kept) * C_;
  float* xo = x2 + ((size_t)b * N2_ + 1 + k) * C_;
  for (int c = t; c < C_; c += 256) {
    const int h = c >> 6;
    float acc = 0.f;
    #pragma unroll 8
    for (int e = 0; e < NP_; ++e)
      acc += ws_[h * NP_ + e] * x1[((size_t)b * N_ + es[e]) * C_ + c];
    xo[c] = xk[c] + ALPHA_ * acc;
  }
}

// ---------------------------------------------------------------------------
// Launcher
// ---------------------------------------------------------------------------
extern "C" void kernel_launch(void* const* d_in, const int* in_sizes, int n_in,
                              void* d_out, int out_size, void* d_ws, size_t ws_size,
                              hipStream_t stream)
{
  const float* x     = (const float*)d_in[0];
  const float* n1w   = (const float*)d_in[1];
  const float* n1b   = (const float*)d_in[2];
  const float* qkvw  = (const float*)d_in[3];
  const float* projw = (const float*)d_in[4];
  const float* projb = (const float*)d_in[5];
  const float* n2w   = (const float*)d_in[6];
  const float* n2b   = (const float*)d_in[7];
  const float* fc1w  = (const float*)d_in[8];
  const float* fc1b  = (const float*)d_in[9];
  const float* fc2w  = (const float*)d_in[10];
  const float* fc2b  = (const float*)d_in[11];
  float* outp = (float*)d_out;

  char* ws = (char*)d_ws;
  __bf16* xa_hi = (__bf16*)(ws + OFFB_XAHI);
  __bf16* xa_lo = (__bf16*)(ws + OFFB_XALO);
  float*  attn  = (float*)(ws + OFFB_ATTN);
  __bf16* fc1h  = (__bf16*)(ws + OFFB_FC1H);
  __bf16* h2    = (__bf16*)(ws + OFFB_H2);
  __bf16* fc1wb = (__bf16*)(ws + OFFB_FC1W);
  __bf16* fc2wb = (__bf16*)(ws + OFFB_FC2W);
  __bf16* qhi   = (__bf16*)(ws + OFFB_QHI);
  __bf16* qlo   = (__bf16*)(ws + OFFB_QLO);
  __bf16* vb    = (__bf16*)(ws + OFFB_VB);
  float*  x1    = (float*)(ws + OFFB_X1);
  __bf16* aout  = (__bf16*)(ws + OFFB_AOUT);
  float*  wbuf  = (float*)(ws + OFFB_WBUF);
  __bf16* qwhi  = (__bf16*)(ws + OFFB_QWHI);
  __bf16* qwlo  = (__bf16*)(ws + OFFB_QWLO);
  __bf16* prjwb = (__bf16*)(ws + OFFB_PRJW);
  float*  sig   = (float*)(ws + OFFB_SIG);
  float*  wsig  = (float*)(ws + OFFB_WSIG);
  float*  tr    = (float*)(ws + OFFB_TR);
  int*    ord   = (int*)(ws + OFFB_ORD);
  float*  x2    = outp;

  // Weight conversions needed early
  wsplit_kernel<<<(2304 * 768 + 255) / 256, 256, 0, stream>>>(
      qkvw, qwhi, qwlo, 2304 * 768);
  wconv_kernel<<<(768 * 768 + 255) / 256, 256, 0, stream>>>(
      projw, prjwb, 768 * 768);
  // 1. LN1 -> split bf16 (pad rows zeroed)
  ln_bf16_kernel<<<M1P_, 256, 0, stream>>>(x, n1w, n1b, xa_hi, xa_lo, M1_);
  // 2a. q,k = split GEMM (N=1536) -> hi/lo bf16
  gemm_split_kernel<<<dim3(1536 / 128, M1P_ / 128), 256, 0, stream>>>(
      xa_hi, xa_lo, qwhi, qwlo, qhi, qlo, 1536, C_);
  // 2b. v = plain bf16 GEMM (N=768) -> bf16
  gemm_bf16_kernel<<<dim3(C_ / 128, M1P_ / 128), 256, 0, stream>>>(
      xa_hi, qwhi + (size_t)1536 * C_, nullptr, nullptr, nullptr, vb,
      M1P_, C_, C_, 0);
  // 3. scores via split MFMA (attn overwrites xa region; xa dead)
  scores_mfma_kernel<<<B_ * H_, 256, 0, stream>>>(qhi, qlo, attn);
  // 4. softmax
  softmax_kernel<<<(B_ * H_ * N_) / 4, 256, 0, stream>>>(attn);
  // 5. sigma per (b,h) — attn stays PRE-threshold; consumers compare vs sig
  radix_select_kernel<<<B_ * H_, 256, 0, stream>>>(attn, N_ * N_, KASC_ATTN,
                                                   N_ * N_, sig);
  // 6. attn @ v via MFMA (threshold folded into staging) -> aout bf16
  attn_v_mfma_kernel<<<dim3(B_ * H_, 4), 256, 0, stream>>>(attn, sig, vb, aout);
  // 7. token_rank (thresholded diag) + stable order
  token_rank_kernel<<<B_, 256, 0, stream>>>(attn, sig, tr);
  order_kernel<<<B_, 256, 0, stream>>>(tr, ord);
  // 8. x1 = x + aout @ proj_w.T + proj_b (fp32)
  gemm_bf16_kernel<<<dim3(C_ / 128, M1P_ / 128), 256, 0, stream>>>(
      aout, prjwb, projb, x, x1, nullptr, M1_, C_, C_, 0);
  // 9. w gather (threshold folded) + w_sigma + w threshold
  {
    const int total = B_ * H_ * NK_ * NP_;
    w_gather_kernel<<<(total + 255) / 256, 256, 0, stream>>>(attn, sig, ord, wbuf);
    radix_select_kernel<<<B_ * H_, 256, 0, stream>>>(wbuf, NK_ * NP_, KASC_W,
                                                     NK_ * NP_, wsig);
    threshold_kernel<<<(total + 255) / 256, 256, 0, stream>>>(wbuf, wsig, total,
                                                              NK_ * NP_);
  }
  // attn now dead -> convert fc1/fc2 weights into tail of region A
  wconv_kernel<<<(MLP_ * C_ + 255) / 256, 256, 0, stream>>>(
      fc1w, fc1wb, MLP_ * C_);
  wconv_kernel<<<(C_ * MLP_ + 255) / 256, 256, 0, stream>>>(
      fc2w, fc2wb, C_ * MLP_);
  // 10. x_prop + assemble x2 (d_out)
  xprop_kernel<<<dim3(N2_, B_), 256, 0, stream>>>(x1, wbuf, ord, x2);
  // 11. LN2 -> bf16 (pad rows zeroed)
  ln_bf16_kernel<<<M2P_, 256, 0, stream>>>(x2, n2w, n2b, h2, nullptr, M2_);
  // 12. fc1 + bias + gelu -> bf16
  gemm_bf16_kernel<<<dim3(MLP_ / 128, M2P_ / 128), 256, 0, stream>>>(
      h2, fc1wb, fc1b, nullptr, nullptr, fc1h, M2P_, MLP_, C_, 1);
  // 13. out = x2 + fc1h @ fc2_w.T + fc2_b (in-place on d_out)
  gemm_bf16_kernel<<<dim3(C_ / 128, M2P_ / 128), 256, 0, stream>>>(
      fc1h, fc2wb, fc2b, x2, outp, nullptr, M2_, C_, MLP_, 0);
}